// Round 1
// baseline (199.165 us; speedup 1.0000x reference)
//
#include <hip/hip_runtime.h>
#include <math.h>

#define NB 8192      // batch rows
#define NC 1000      // classes
#define NF4 250      // NC / 4 float4s per row

// ws layout (floats, stride NB):
//  [0..4]   margin per branch
//  [5..9]   gathered (raw) per branch
//  [10..14] KD per branch
//  [15]     CE
//  [16]     row min of gathered over 4 real teachers
//  [17]     row max of row-maxes over 4 real teachers

#define LOG2E 1.4426950408889634f
#define LN2   0.6931471805599453f

__device__ __forceinline__ float fexp2(float x) { return __builtin_amdgcn_exp2f(x); }
__device__ __forceinline__ float flog2(float x) { return __builtin_amdgcn_logf(x); }

// ---------------- DPP wave reductions (VALU pipe, not DS) ----------------
// row_shr 1/2/4/8 within 16-lane rows, then row_bcast:15 and row_bcast:31.
// Full-wave result lands in lane 63. Invalid source lanes take `ident`.
template <int CTRL>
__device__ __forceinline__ float dpp_mov(float v, float ident) {
  return __uint_as_float((unsigned)__builtin_amdgcn_update_dpp(
      (int)__float_as_uint(ident), (int)__float_as_uint(v), CTRL, 0xF, 0xF,
      false));
}

__device__ __forceinline__ float dppredsum(float v) {
  v += dpp_mov<0x111>(v, 0.f);
  v += dpp_mov<0x112>(v, 0.f);
  v += dpp_mov<0x114>(v, 0.f);
  v += dpp_mov<0x118>(v, 0.f);
  v += dpp_mov<0x142>(v, 0.f);
  v += dpp_mov<0x143>(v, 0.f);
  return v;  // lane 63 = full sum
}

__device__ __forceinline__ void dppredtop2(float& t1, float& t2) {
  const float NI = -INFINITY;
#define T2STEP(C)                                   \
  {                                                 \
    float i1 = dpp_mov<C>(t1, NI);                  \
    float i2 = dpp_mov<C>(t2, NI);                  \
    t2 = fmaxf(fmaxf(t2, i2), fminf(t1, i1));       \
    t1 = fmaxf(t1, i1);                             \
  }
  T2STEP(0x111) T2STEP(0x112) T2STEP(0x114) T2STEP(0x118)
  T2STEP(0x142) T2STEP(0x143)
#undef T2STEP
  // lane 63 = (max, runner-up)
}

// shfl-based helpers (only used in the small finalize kernel)
__device__ __forceinline__ float wredsum(float v) {
#pragma unroll
  for (int m = 32; m >= 1; m >>= 1) v += __shfl_xor(v, m, 64);
  return v;
}
__device__ __forceinline__ float wredmax(float v) {
#pragma unroll
  for (int m = 32; m >= 1; m >>= 1) v = fmaxf(v, __shfl_xor(v, m, 64));
  return v;
}
__device__ __forceinline__ float wredmin(float v) {
#pragma unroll
  for (int m = 32; m >= 1; m >>= 1) v = fminf(v, __shfl_xor(v, m, 64));
  return v;
}
__device__ __forceinline__ float f4get(const float4& v, int e) {
  return e == 0 ? v.x : e == 1 ? v.y : e == 2 ? v.z : v.w;
}

// ONE WAVE per row (4 rows per 256-block). Amortizes the 22 DPP wave
// reductions over 16 elems/lane instead of 4 (R6 theory: reductions were
// ~2/3 of the VALU work in the 4-wave-per-row layout). No LDS, no
// __syncthreads, no serial thread-0 cross-wave tail.
__global__ __launch_bounds__(256, 8) void k_rowstats(
    const float* __restrict__ o1, const float* __restrict__ o2,
    const float* __restrict__ o3, const float* __restrict__ o4,
    const float* __restrict__ os, const int* __restrict__ tg,
    float* __restrict__ ws, float* __restrict__ out) {
  const int lane = threadIdx.x & 63;
  const int wv = threadIdx.x >> 6;          // 0..3
  const int row = (blockIdx.x << 2) + wv;   // grid = NB/4
  const size_t base = (size_t)row * NC;

  // zero the output accumulator for k_final's atomics (runs strictly before)
  if (blockIdx.x == 0 && threadIdx.x == 0) out[0] = 0.0f;

  float t1[5], t2[5], Z[5], S1[5];
#pragma unroll
  for (int t = 0; t < 5; ++t) {
    t1[t] = -INFINITY; t2[t] = -INFINITY; Z[t] = 0.f; S1[t] = 0.f;
  }
  float Z1 = 0.f, Z20 = 0.f;
  const float K20 = LOG2E / 20.0f;

#pragma unroll 1
  for (int i = 0; i < 4; ++i) {
    const int f = lane + (i << 6);     // float4 index, 0..255 (250 valid)
    if (f < NF4) {
      const float4 c1 = ((const float4*)(o1 + base))[f];
      const float4 c2 = ((const float4*)(o2 + base))[f];
      const float4 c3 = ((const float4*)(o3 + base))[f];
      const float4 c4 = ((const float4*)(o4 + base))[f];
      const float4 cs = ((const float4*)(os + base))[f];
#pragma unroll
      for (int e = 0; e < 4; ++e) {
        float w0 = f4get(c1, e);
        float w1 = f4get(c2, e);
        float w2 = f4get(c3, e);
        float w3 = f4get(c4, e);
        float wsv = f4get(cs, e);
        float wm = ((w0 + w1) + w2 + w3) * 0.25f;  // mimic — keep this op order
        float w[5] = {w0, w1, w2, w3, wm};
#pragma unroll
        for (int t = 0; t < 5; ++t) {
          t2[t] = fmaxf(t2[t], fminf(t1[t], w[t]));
          t1[t] = fmaxf(t1[t], w[t]);
          float et = fexp2(w[t] * K20);
          Z[t] += et;
          S1[t] = fmaf(et, w[t] - wsv, S1[t]);
        }
        Z1 += fexp2(wsv * LOG2E);
        Z20 += fexp2(wsv * K20);
      }
    }
  }

  // target gathers issued here: their latency hides under the ~260-instr
  // DPP reduction chain below (uniform address per wave -> broadcast load)
  const int target = tg[row];
  const float g1 = o1[base + target];
  const float g2 = o2[base + target];
  const float g3 = o3[base + target];
  const float g4 = o4[base + target];
  const float gs = os[base + target];

  // wave-level reductions on the VALU pipe (result in lane 63)
#pragma unroll
  for (int t = 0; t < 5; ++t) dppredtop2(t1[t], t2[t]);
#pragma unroll
  for (int t = 0; t < 5; ++t) { Z[t] = dppredsum(Z[t]); S1[t] = dppredsum(S1[t]); }
  Z1 = dppredsum(Z1);
  Z20 = dppredsum(Z20);

  if (lane == 63) {
    const float gm = ((g1 + g2) + g3 + g4) * 0.25f;  // same op order as wm
    float gg[5] = {g1, g2, g3, g4, gm};

    const float lse_s = flog2(Z20) * LN2;     // logsumexp(out_s/20), unshifted
    const float CE = flog2(Z1) * LN2 - gs;    // -log_softmax(out_s)[target]

#pragma unroll
    for (int t = 0; t < 5; ++t) {
      float lse_t = flog2(Z[t]) * LN2;
      float KD = 400.0f * (S1[t] / (20.0f * Z[t]) - lse_t + lse_s);
      float margin = (t1[t] == gg[t]) ? (t1[t] - t2[t]) : 0.0f;
      ws[(size_t)t * NB + row] = margin;
      ws[(size_t)(5 + t) * NB + row] = gg[t];
      ws[(size_t)(10 + t) * NB + row] = KD;
    }
    ws[(size_t)15 * NB + row] = CE;
    ws[(size_t)16 * NB + row] = fminf(fminf(g1, g2), fminf(g3, g4));
    ws[(size_t)17 * NB + row] = fmaxf(fmaxf(t1[0], t1[1]), fmaxf(t1[2], t1[3]));
  }
}

// Fused minmax + loss: every block REDUNDANTLY scans the 64 KB min/max
// columns (L2/L3-resident after k_rowstats -> ~free), so no single-block
// serialization kernel and no extra launch. One atomicAdd per block.
__global__ __launch_bounds__(256) void k_final(const float* __restrict__ ws,
                                               float* __restrict__ out) {
  const int tid = threadIdx.x;
  const int lane = tid & 63, wv = tid >> 6;
  __shared__ float sMn[4], sMx[4], sA[4];

  float mn = INFINITY, mx = -INFINITY;
  const float4* mnp = (const float4*)(ws + (size_t)16 * NB);
  const float4* mxp = (const float4*)(ws + (size_t)17 * NB);
#pragma unroll 1
  for (int r4 = tid; r4 < NB / 4; r4 += 256) {
    float4 a = mnp[r4];
    float4 b = mxp[r4];
    mn = fminf(mn, fminf(fminf(a.x, a.y), fminf(a.z, a.w)));
    mx = fmaxf(mx, fmaxf(fmaxf(b.x, b.y), fmaxf(b.z, b.w)));
  }
  mn = wredmin(mn);
  mx = wredmax(mx);
  if (lane == 0) { sMn[wv] = mn; sMx[wv] = mx; }
  __syncthreads();
  const float a = fminf(fminf(sMn[0], sMn[1]), fminf(sMn[2], sMn[3]));
  const float b = fmaxf(fmaxf(sMx[0], sMx[1]), fmaxf(sMx[2], sMx[3]));
  const float shift = (a < 0.0f) ? (-a + 1e-5f) : 0.0f;
  const float maxp = b + shift;

  const int r = blockIdx.x * 256 + tid;   // 32 blocks x 256 = 8192 rows
  const float K6 = LOG2E / 6.0f;

  float m[5], e[5];
#pragma unroll
  for (int t = 0; t < 5; ++t) m[t] = ws[(size_t)t * NB + r];
  float pm = fmaxf(fmaxf(fmaxf(m[0], m[1]), fmaxf(m[2], m[3])), m[4]);
  float Zl = 0.0f;
#pragma unroll
  for (int t = 0; t < 5; ++t) { e[t] = fexp2((m[t] - pm) * K6); Zl += e[t]; }
  float ce = ws[(size_t)15 * NB + r];
  float rl = 0.0f;
#pragma unroll
  for (int t = 0; t < 5; ++t) {
    float g = ws[(size_t)(5 + t) * NB + r];
    float kd = ws[(size_t)(10 + t) * NB + r];
    float w2 = (g + shift) / maxp;
    float loss = (1.0f - w2) * ce + w2 * kd;
    rl += e[t] * loss;
  }
  float acc = rl / Zl;

  acc = wredsum(acc);
  if (lane == 0) sA[wv] = acc;
  __syncthreads();
  if (tid == 0) {
    float tot = (sA[0] + sA[1]) + (sA[2] + sA[3]);
    atomicAdd(out, tot * (1.0f / 8192.0f));
  }
}

extern "C" void kernel_launch(void* const* d_in, const int* in_sizes, int n_in,
                              void* d_out, int out_size, void* d_ws, size_t ws_size,
                              hipStream_t stream) {
  const float* o1 = (const float*)d_in[0];
  const float* o2 = (const float*)d_in[1];
  const float* o3 = (const float*)d_in[2];
  const float* o4 = (const float*)d_in[3];
  const float* os = (const float*)d_in[4];
  const int* tg = (const int*)d_in[5];
  float* ws = (float*)d_ws;
  float* out = (float*)d_out;

  k_rowstats<<<NB / 4, 256, 0, stream>>>(o1, o2, o3, o4, os, tg, ws, out);
  k_final<<<NB / 256, 256, 0, stream>>>(ws, out);
}

// Round 2
// 185.567 us; speedup vs baseline: 1.0733x; 1.0733x over previous
//
#include <hip/hip_runtime.h>
#include <math.h>

#define NB 8192      // batch rows
#define NC 1000      // classes
#define NF4 250      // NC / 4 float4s per row

// ws layout (floats, stride NB):
//  [0..4]   margin per branch
//  [5..9]   gathered (raw) per branch
//  [10..14] KD per branch
//  [15]     CE
//  [16]     row min of gathered over 4 real teachers
//  [17]     row max of row-maxes over 4 real teachers

#define LOG2E 1.4426950408889634f
#define LN2   0.6931471805599453f

__device__ __forceinline__ float fexp2(float x) { return __builtin_amdgcn_exp2f(x); }
__device__ __forceinline__ float flog2(float x) { return __builtin_amdgcn_logf(x); }

// ---------------- DPP wave reductions (VALU pipe, not DS) ----------------
// row_shr 1/2/4/8 within 16-lane rows, then row_bcast:15 and row_bcast:31.
// Full-wave result lands in lane 63. Invalid source lanes take `ident`.
template <int CTRL>
__device__ __forceinline__ float dpp_mov(float v, float ident) {
  return __uint_as_float((unsigned)__builtin_amdgcn_update_dpp(
      (int)__float_as_uint(ident), (int)__float_as_uint(v), CTRL, 0xF, 0xF,
      false));
}

__device__ __forceinline__ float dppredsum(float v) {
  v += dpp_mov<0x111>(v, 0.f);
  v += dpp_mov<0x112>(v, 0.f);
  v += dpp_mov<0x114>(v, 0.f);
  v += dpp_mov<0x118>(v, 0.f);
  v += dpp_mov<0x142>(v, 0.f);
  v += dpp_mov<0x143>(v, 0.f);
  return v;  // lane 63 = full sum
}

__device__ __forceinline__ void dppredtop2(float& t1, float& t2) {
  const float NI = -INFINITY;
#define T2STEP(C)                                   \
  {                                                 \
    float i1 = dpp_mov<C>(t1, NI);                  \
    float i2 = dpp_mov<C>(t2, NI);                  \
    t2 = fmaxf(fmaxf(t2, i2), fminf(t1, i1));       \
    t1 = fmaxf(t1, i1);                             \
  }
  T2STEP(0x111) T2STEP(0x112) T2STEP(0x114) T2STEP(0x118)
  T2STEP(0x142) T2STEP(0x143)
#undef T2STEP
  // lane 63 = (max, runner-up)
}

// shfl-based helpers (only used in the small finalize kernel)
__device__ __forceinline__ float wredsum(float v) {
#pragma unroll
  for (int m = 32; m >= 1; m >>= 1) v += __shfl_xor(v, m, 64);
  return v;
}
__device__ __forceinline__ float wredmax(float v) {
#pragma unroll
  for (int m = 32; m >= 1; m >>= 1) v = fmaxf(v, __shfl_xor(v, m, 64));
  return v;
}
__device__ __forceinline__ float wredmin(float v) {
#pragma unroll
  for (int m = 32; m >= 1; m >>= 1) v = fminf(v, __shfl_xor(v, m, 64));
  return v;
}
__device__ __forceinline__ float f4get(const float4& v, int e) {
  return e == 0 ? v.x : e == 1 ? v.y : e == 2 ? v.z : v.w;
}

// Per-chunk accumulate (4 elements x 5 branches)
__device__ __forceinline__ void proc_chunk(
    const float4& c1, const float4& c2, const float4& c3, const float4& c4,
    const float4& cs, float t1[5], float t2[5], float Z[5], float S1[5],
    float& Z1, float& Z20) {
  const float K20 = LOG2E / 20.0f;
#pragma unroll
  for (int e = 0; e < 4; ++e) {
    float w0 = f4get(c1, e);
    float w1 = f4get(c2, e);
    float w2 = f4get(c3, e);
    float w3 = f4get(c4, e);
    float wsv = f4get(cs, e);
    float wm = ((w0 + w1) + w2 + w3) * 0.25f;  // mimic — keep this op order
    float w[5] = {w0, w1, w2, w3, wm};
#pragma unroll
    for (int t = 0; t < 5; ++t) {
      t2[t] = fmaxf(t2[t], fminf(t1[t], w[t]));
      t1[t] = fmaxf(t1[t], w[t]);
      float et = fexp2(w[t] * K20);
      Z[t] += et;
      S1[t] = fmaf(et, w[t] - wsv, S1[t]);
    }
    Z1 += fexp2(wsv * LOG2E);
    Z20 += fexp2(wsv * K20);
  }
}

// ONE WAVE per row (4 rows per 256-block), ALL 20 float4 loads hoisted into
// registers up front (R1 post-mortem: `unroll 1` loop serialized 4 memory
// round-trips -> latency-bound at 24% VALU / 20% HBM). Chunk-3 loads use a
// clamped index (dup of f=249) so no branches sit between the load burst;
// only chunk-3's accumulate is lane-guarded. 128-VGPR cap via (256,4).
__global__ __launch_bounds__(256, 4) void k_rowstats(
    const float* __restrict__ o1, const float* __restrict__ o2,
    const float* __restrict__ o3, const float* __restrict__ o4,
    const float* __restrict__ os, const int* __restrict__ tg,
    float* __restrict__ ws, float* __restrict__ out) {
  const int lane = threadIdx.x & 63;
  const int wv = threadIdx.x >> 6;          // 0..3
  const int row = (blockIdx.x << 2) + wv;   // grid = NB/4
  const size_t base = (size_t)row * NC;

  // zero the output accumulator for k_final's atomics (runs strictly before)
  if (blockIdx.x == 0 && threadIdx.x == 0) out[0] = 0.0f;

  // target gathers issued first (oldest in vmem queue; needed only at end)
  const int target = tg[row];
  const float g1 = o1[base + target];
  const float g2 = o2[base + target];
  const float g3 = o3[base + target];
  const float g4 = o4[base + target];
  const float gs = os[base + target];

  // bulk loads: 20 float4s, all in flight at once (one round-trip per wave)
  float4 A1[4], A2[4], A3[4], A4[4], AS[4];
#pragma unroll
  for (int i = 0; i < 4; ++i) {
    int f = lane + (i << 6);
    if (f > NF4 - 1) f = NF4 - 1;           // clamp: safe dup load, masked below
    A1[i] = ((const float4*)(o1 + base))[f];
    A2[i] = ((const float4*)(o2 + base))[f];
    A3[i] = ((const float4*)(o3 + base))[f];
    A4[i] = ((const float4*)(o4 + base))[f];
    AS[i] = ((const float4*)(os + base))[f];
  }

  float t1[5], t2[5], Z[5], S1[5];
#pragma unroll
  for (int t = 0; t < 5; ++t) {
    t1[t] = -INFINITY; t2[t] = -INFINITY; Z[t] = 0.f; S1[t] = 0.f;
  }
  float Z1 = 0.f, Z20 = 0.f;

  proc_chunk(A1[0], A2[0], A3[0], A4[0], AS[0], t1, t2, Z, S1, Z1, Z20);
  proc_chunk(A1[1], A2[1], A3[1], A4[1], AS[1], t1, t2, Z, S1, Z1, Z20);
  proc_chunk(A1[2], A2[2], A3[2], A4[2], AS[2], t1, t2, Z, S1, Z1, Z20);
  if (lane < 58)  // chunk 3: f = lane+192 < 250
    proc_chunk(A1[3], A2[3], A3[3], A4[3], AS[3], t1, t2, Z, S1, Z1, Z20);

  // wave-level reductions on the VALU pipe (result in lane 63)
#pragma unroll
  for (int t = 0; t < 5; ++t) dppredtop2(t1[t], t2[t]);
#pragma unroll
  for (int t = 0; t < 5; ++t) { Z[t] = dppredsum(Z[t]); S1[t] = dppredsum(S1[t]); }
  Z1 = dppredsum(Z1);
  Z20 = dppredsum(Z20);

  if (lane == 63) {
    const float gm = ((g1 + g2) + g3 + g4) * 0.25f;  // same op order as wm
    float gg[5] = {g1, g2, g3, g4, gm};

    const float lse_s = flog2(Z20) * LN2;     // logsumexp(out_s/20), unshifted
    const float CE = flog2(Z1) * LN2 - gs;    // -log_softmax(out_s)[target]

#pragma unroll
    for (int t = 0; t < 5; ++t) {
      float lse_t = flog2(Z[t]) * LN2;
      float KD = 400.0f * (S1[t] / (20.0f * Z[t]) - lse_t + lse_s);
      float margin = (t1[t] == gg[t]) ? (t1[t] - t2[t]) : 0.0f;
      ws[(size_t)t * NB + row] = margin;
      ws[(size_t)(5 + t) * NB + row] = gg[t];
      ws[(size_t)(10 + t) * NB + row] = KD;
    }
    ws[(size_t)15 * NB + row] = CE;
    ws[(size_t)16 * NB + row] = fminf(fminf(g1, g2), fminf(g3, g4));
    ws[(size_t)17 * NB + row] = fmaxf(fmaxf(t1[0], t1[1]), fmaxf(t1[2], t1[3]));
  }
}

// Fused minmax + loss: every block REDUNDANTLY scans the 64 KB min/max
// columns (L2/L3-resident after k_rowstats -> ~free), so no single-block
// serialization kernel and no extra launch. One atomicAdd per block.
__global__ __launch_bounds__(256) void k_final(const float* __restrict__ ws,
                                               float* __restrict__ out) {
  const int tid = threadIdx.x;
  const int lane = tid & 63, wv = tid >> 6;
  __shared__ float sMn[4], sMx[4], sA[4];

  float mn = INFINITY, mx = -INFINITY;
  const float4* mnp = (const float4*)(ws + (size_t)16 * NB);
  const float4* mxp = (const float4*)(ws + (size_t)17 * NB);
#pragma unroll 1
  for (int r4 = tid; r4 < NB / 4; r4 += 256) {
    float4 a = mnp[r4];
    float4 b = mxp[r4];
    mn = fminf(mn, fminf(fminf(a.x, a.y), fminf(a.z, a.w)));
    mx = fmaxf(mx, fmaxf(fmaxf(b.x, b.y), fmaxf(b.z, b.w)));
  }
  mn = wredmin(mn);
  mx = wredmax(mx);
  if (lane == 0) { sMn[wv] = mn; sMx[wv] = mx; }
  __syncthreads();
  const float a = fminf(fminf(sMn[0], sMn[1]), fminf(sMn[2], sMn[3]));
  const float b = fmaxf(fmaxf(sMx[0], sMx[1]), fmaxf(sMx[2], sMx[3]));
  const float shift = (a < 0.0f) ? (-a + 1e-5f) : 0.0f;
  const float maxp = b + shift;

  const int r = blockIdx.x * 256 + tid;   // 32 blocks x 256 = 8192 rows
  const float K6 = LOG2E / 6.0f;

  float m[5], e[5];
#pragma unroll
  for (int t = 0; t < 5; ++t) m[t] = ws[(size_t)t * NB + r];
  float pm = fmaxf(fmaxf(fmaxf(m[0], m[1]), fmaxf(m[2], m[3])), m[4]);
  float Zl = 0.0f;
#pragma unroll
  for (int t = 0; t < 5; ++t) { e[t] = fexp2((m[t] - pm) * K6); Zl += e[t]; }
  float ce = ws[(size_t)15 * NB + r];
  float rl = 0.0f;
#pragma unroll
  for (int t = 0; t < 5; ++t) {
    float g = ws[(size_t)(5 + t) * NB + r];
    float kd = ws[(size_t)(10 + t) * NB + r];
    float w2 = (g + shift) / maxp;
    float loss = (1.0f - w2) * ce + w2 * kd;
    rl += e[t] * loss;
  }
  float acc = rl / Zl;

  acc = wredsum(acc);
  if (lane == 0) sA[wv] = acc;
  __syncthreads();
  if (tid == 0) {
    float tot = (sA[0] + sA[1]) + (sA[2] + sA[3]);
    atomicAdd(out, tot * (1.0f / 8192.0f));
  }
}

extern "C" void kernel_launch(void* const* d_in, const int* in_sizes, int n_in,
                              void* d_out, int out_size, void* d_ws, size_t ws_size,
                              hipStream_t stream) {
  const float* o1 = (const float*)d_in[0];
  const float* o2 = (const float*)d_in[1];
  const float* o3 = (const float*)d_in[2];
  const float* o4 = (const float*)d_in[3];
  const float* os = (const float*)d_in[4];
  const int* tg = (const int*)d_in[5];
  float* ws = (float*)d_ws;
  float* out = (float*)d_out;

  k_rowstats<<<NB / 4, 256, 0, stream>>>(o1, o2, o3, o4, os, tg, ws, out);
  k_final<<<NB / 256, 256, 0, stream>>>(ws, out);
}